// Round 2
// baseline (9373.095 us; speedup 1.0000x reference)
//
#include <hip/hip_runtime.h>
#include <math.h>

#define NPTS   20001
#define NREAL  20000
#define EPAD   1200000
#define KK     64
#define RADF   0.1125f

__device__ __forceinline__ float sgnf(float v){ return v>0.f ? 1.f : (v<0.f ? -1.f : 0.f); }

// LDS float atomic add. unsafeAtomicAdd -> native ds_add_f32 on CDNA (no return form,
// no lgkmcnt dependency in the scatter loop). Race-free -> no z-parity wave split needed.
__device__ __forceinline__ void lds_add(float* p, float v){ unsafeAtomicAdd(p, v); }

// ---------------- CSR build (edge_src is sorted; pad edges have dst==NREAL) ----------------
__global__ void k_find_ereal(const int* __restrict__ dst, int* __restrict__ ereal){
  int lo=0, hi=EPAD;
  while(lo<hi){ int mid=(lo+hi)>>1; if(dst[mid]==NREAL) hi=mid; else lo=mid+1; }
  *ereal = lo;
}

__global__ void k_csr(const int* __restrict__ src, const int* __restrict__ erealp,
                      int* __restrict__ row_start){
  int i = blockIdx.x*blockDim.x + threadIdx.x;
  if(i > NPTS) return;
  int E = *erealp;
  int lo=0, hi=E;
  while(lo<hi){ int mid=(lo+hi)>>1; if(src[mid] < i) lo=mid+1; else hi=mid; }
  row_start[i] = lo;
}

__global__ void k_build_f(const float* __restrict__ feats, float* __restrict__ f){
  int idx = blockIdx.x*blockDim.x + threadIdx.x;
  if(idx >= NPTS*13) return;
  int i = idx/13, c = idx - i*13;
  f[idx] = (c==0) ? 1.f : feats[i*12 + (c-1)];
}

// ---------------- per-edge geometry (exact port of ball_to_cube + window) ----------------
__device__ __forceinline__ void edge_geom(float ox, float oy, float oz,
                                          float& win, float& t0, float& t1, float& t2, int& f0p){
  const float eps = 1e-9f;
  float sq = ox*ox + oy*oy + oz*oz;
  float u = 1.f - sq;
  win = fminf(fmaxf(u*u*u, 0.f), 1.f);
  float norm = sqrtf(sq + eps);
  float rxy2 = ox*ox + oy*oy;
  bool polar = (1.25f*oz*oz > rxy2);
  float s_p = sqrtf(3.f*norm/(norm + fabsf(oz) + eps));
  float s_n = norm / sqrtf(rxy2 + eps);
  float s = polar ? s_p : s_n;
  float xc = ox*s, yc = oy*s;
  float zc = polar ? sgnf(oz)*norm : 1.5f*oz;
  if(sq < 1e-12f){ xc = 0.f; yc = 0.f; zc = 0.f; }
  float r = sqrtf(xc*xc + yc*yc + eps);
  bool c1 = fabsf(xc) >= fabsf(yc);
  float xs = (fabsf(xc) < eps) ? eps : xc;
  float ys = (fabsf(yc) < eps) ? eps : yc;
  const float fop = 1.2732395447351628f; // float32(4/pi)
  float a = c1 ? sgnf(xc)*r : sgnf(yc)*r*fop*atanf(xc/ys);
  float b = c1 ? sgnf(xc)*r*fop*atanf(yc/xs) : sgnf(yc)*r;
  if(xc*xc + yc*yc < 1e-12f){ a = 0.f; b = 0.f; }
  float g0 = fminf(fmaxf((a *0.5f+0.5f)*3.f, 0.f), 3.f);
  float g1 = fminf(fmaxf((b *0.5f+0.5f)*3.f, 0.f), 3.f);
  float g2 = fminf(fmaxf((zc*0.5f+0.5f)*3.f, 0.f), 3.f);
  float f00 = floorf(g0), f01 = floorf(g1), f02 = floorf(g2);
  t0 = g0 - f00; t1 = g1 - f01; t2 = g2 - f02;
  f0p = (int)f00 | ((int)f01 << 2) | ((int)f02 << 4);
}

// ---- k_geom: per-edge staged data, computed ONCE (shared by all 4 scatter layers).
// gw[e]  = win-premultiplied xy-quad weights {q00,q01,q10,q11}
// gmz[e] = {bits(zA), cells0, cells1, dst}; zB = 1-zA (wz0+wz1==1 exactly).
// min(i+1,3) -> (i+1)&3 is exact (clamped corner has t==0 weight): all 8 cells distinct.
// cells0 = even-z cells (weight zA), cells1 = odd-z cells (weight 1-zA).
__global__ __launch_bounds__(256) void k_geom(const float* __restrict__ pos,
    const int* __restrict__ esrc, const int* __restrict__ edst,
    float4* __restrict__ gw, int4* __restrict__ gmz)
{
  int e = blockIdx.x*blockDim.x + threadIdx.x;
  if(e >= EPAD) return;
  const int sn = esrc[e], d = edst[e];
  const float ox = (pos[d*3+0]-pos[sn*3+0])/RADF;
  const float oy = (pos[d*3+1]-pos[sn*3+1])/RADF;
  const float oz = (pos[d*3+2]-pos[sn*3+2])/RADF;
  float win, t0, t1, t2; int f0p;
  edge_geom(ox, oy, oz, win, t0, t1, t2, f0p);
  const int i0 = f0p & 3, i1 = (f0p>>2) & 3, i2 = f0p >> 4;
  const int X0 = i0 << 4, X1 = ((i0+1)&3) << 4;
  const int Y0 = i1 << 2, Y1 = ((i1+1)&3) << 2;
  const int Z0 = i2, Z1 = (i2+1) & 3;
  const float wx0 = win*(1.f-t0), wx1 = win*t0;
  const float wy0 = 1.f-t1, wy1 = t1;
  const float wz0 = 1.f-t2, wz1 = t2;
  gw[e] = make_float4(wx0*wy0, wx0*wy1, wx1*wy0, wx1*wy1);
  const int p0 = Z0 & 1;
  const float zA = p0 ? wz1 : wz0;                  // weight for even-z cell
  const int   cA = p0 ? Z1 : Z0;                    // even-z cell
  const int   cB = p0 ? Z0 : Z1;                    // odd-z cell
  const int cells0 = (X0|Y0|cA) | ((X0|Y1|cA)<<8) | ((X1|Y0|cA)<<16) | ((X1|Y1|cA)<<24);
  const int cells1 = (X0|Y0|cB) | ((X0|Y1|cB)<<8) | ((X1|Y0|cB)<<16) | ((X1|Y1|cB)<<24);
  gmz[e] = make_int4(__float_as_int(zA), cells0, cells1, d);
}

// ------- scatter CIN=64: 2 waves, each owns HALF THE EDGES (interleaved), all 8 cells
// per edge via ds_add_f32 (atomic, no-return -> no RMW dependency, race-free).
// 8 LDS ops/edge total vs 16 for the old RMW z-parity scheme.
// OUT3=1: fused cout=3 GEMV epilogue (layer 3).
template<int RELU, int OUT3>
__global__ __launch_bounds__(128) void k_scat64(
    const float* __restrict__ feat, const float4* __restrict__ gw,
    const int4* __restrict__ gmz, const int* __restrict__ row_start,
    float* __restrict__ B, int node_base,
    const float* __restrict__ W3, float* __restrict__ out)
{
  constexpr int BSZ = 64*64;
  __shared__ __align__(16) float Bl[BSZ];
  __shared__ float red[OUT3 ? 384 : 4];
  const int tid  = threadIdx.x;
  const int node = node_base + blockIdx.x;

  for(int j = tid*4; j < BSZ; j += 512)
    *(float4*)&Bl[j] = make_float4(0.f,0.f,0.f,0.f);

  const int e0 = row_start[node], e1 = row_start[node+1];
  const int wv = tid >> 6;          // this wave's edge-interleave slot
  const int c  = tid & 63;          // owned channel
  __syncthreads();

  #pragma unroll 2
  for(int e = e0 + wv; e < e1; e += 2){
    const float4 q  = gw[e];
    const int4   md = gmz[e];
    const float zA = __int_as_float(md.x);
    const float zB = 1.f - zA;
    float v = feat[(size_t)md.w*64 + c];
    if(RELU) v = fmaxf(v, 0.f);
    const float vA = v*zA, vB = v*zB;
    const int cp0 = md.y, cp1 = md.z;
    lds_add(&Bl[(( cp0        & 255) << 6) + c], q.x*vA);
    lds_add(&Bl[(((cp0 >> 8)  & 255) << 6) + c], q.y*vA);
    lds_add(&Bl[(((cp0 >> 16) & 255) << 6) + c], q.z*vA);
    lds_add(&Bl[((((unsigned)cp0) >> 24) << 6) + c], q.w*vA);
    lds_add(&Bl[(( cp1        & 255) << 6) + c], q.x*vB);
    lds_add(&Bl[(((cp1 >> 8)  & 255) << 6) + c], q.y*vB);
    lds_add(&Bl[(((cp1 >> 16) & 255) << 6) + c], q.z*vB);
    lds_add(&Bl[((((unsigned)cp1) >> 24) << 6) + c], q.w*vB);
  }
  __syncthreads();

  if(!OUT3){
    float* Bg = B + (size_t)blockIdx.x*BSZ;
    for(int j = tid*4; j < BSZ; j += 512)
      *(float4*)&Bg[j] = *(const float4*)&Bl[j];
  } else {
    float s0=0.f, s1=0.f, s2=0.f;
    for(int j = tid; j < BSZ; j += 128){
      float v = Bl[j];
      s0 = fmaf(v, W3[j*3+0], s0);
      s1 = fmaf(v, W3[j*3+1], s1);
      s2 = fmaf(v, W3[j*3+2], s2);
    }
    float* r0 = red; float* r1 = red+128; float* r2 = red+256;
    r0[tid]=s0; r1[tid]=s1; r2[tid]=s2;
    __syncthreads();
    for(int st = 64; st > 0; st >>= 1){
      if(tid < st){ r0[tid]+=r0[tid+st]; r1[tid]+=r1[tid+st]; r2[tid]+=r2[tid+st]; }
      __syncthreads();
    }
    if(tid == 0 && node < NREAL){
      out[node*3+0] += r0[0]*(1.f/128.f);
      out[node*3+1] += r1[0]*(1.f/128.f);
      out[node*3+2] += r2[0]*(1.f/128.f);
    }
  }
}

// ------- scatter CIN=96: 2 waves split edges; channels mapped 64 + 32 (lane<32 carries
// the upper 32 channels too). 12 effective wave-LDS-ops/edge via ds_add_f32.
template<int RELU>
__global__ __launch_bounds__(128) void k_scat96(
    const float* __restrict__ feat, const float4* __restrict__ gw,
    const int4* __restrict__ gmz, const int* __restrict__ row_start,
    float* __restrict__ B, int node_base)
{
  constexpr int CIN = 96, BSZ = KK*CIN;
  __shared__ __align__(16) float Bl[BSZ];
  const int tid  = threadIdx.x;
  const int node = node_base + blockIdx.x;

  for(int j = tid*4; j < BSZ; j += 512)
    *(float4*)&Bl[j] = make_float4(0.f,0.f,0.f,0.f);

  const int e0 = row_start[node], e1 = row_start[node+1];
  const int wv   = tid >> 6;
  const int lane = tid & 63;
  const bool hi  = (lane < 32);   // these lanes also own channel 64+lane
  __syncthreads();

  #pragma unroll 2
  for(int e = e0 + wv; e < e1; e += 2){
    const float4 q  = gw[e];
    const int4   md = gmz[e];
    const float zA = __int_as_float(md.x);
    const float zB = 1.f - zA;
    const float* frow = feat + (size_t)md.w*CIN;
    float v0 = frow[lane];
    float v1 = hi ? frow[64 + lane] : 0.f;
    if(RELU){ v0 = fmaxf(v0,0.f); v1 = fmaxf(v1,0.f); }
    const float v0A = v0*zA, v0B = v0*zB;
    const float v1A = v1*zA, v1B = v1*zB;
    const int cp0 = md.y, cp1 = md.z;
    const int b0 = ( cp0        & 255)*CIN + lane;
    const int b1 = ((cp0 >> 8)  & 255)*CIN + lane;
    const int b2 = ((cp0 >> 16) & 255)*CIN + lane;
    const int b3 = ((((unsigned)cp0) >> 24))*CIN + lane;
    const int b4 = ( cp1        & 255)*CIN + lane;
    const int b5 = ((cp1 >> 8)  & 255)*CIN + lane;
    const int b6 = ((cp1 >> 16) & 255)*CIN + lane;
    const int b7 = ((((unsigned)cp1) >> 24))*CIN + lane;
    lds_add(&Bl[b0], q.x*v0A);
    lds_add(&Bl[b1], q.y*v0A);
    lds_add(&Bl[b2], q.z*v0A);
    lds_add(&Bl[b3], q.w*v0A);
    lds_add(&Bl[b4], q.x*v0B);
    lds_add(&Bl[b5], q.y*v0B);
    lds_add(&Bl[b6], q.z*v0B);
    lds_add(&Bl[b7], q.w*v0B);
    if(hi){
      lds_add(&Bl[b0+64], q.x*v1A);
      lds_add(&Bl[b1+64], q.y*v1A);
      lds_add(&Bl[b2+64], q.z*v1A);
      lds_add(&Bl[b3+64], q.w*v1A);
      lds_add(&Bl[b4+64], q.x*v1B);
      lds_add(&Bl[b5+64], q.y*v1B);
      lds_add(&Bl[b6+64], q.z*v1B);
      lds_add(&Bl[b7+64], q.w*v1B);
    }
  }
  __syncthreads();

  float* Bg = B + (size_t)blockIdx.x*BSZ;
  for(int j = tid*4; j < BSZ; j += 512)
    *(float4*)&Bg[j] = *(const float4*)&Bl[j];
}

// ------- scatter CIN=13: 8 edge-slots (2 waves x 4 slots of 16 lanes), single shared
// accumulator via ds_add_f32 (no slot-private copies, no merge). ~2 wave-LDS-ops/edge.
__global__ __launch_bounds__(128) void k_scat13(
    const float* __restrict__ feat, const float4* __restrict__ gw,
    const int4* __restrict__ gmz, const int* __restrict__ row_start,
    float* __restrict__ B, int node_base)
{
  constexpr int CIN = 13, BSZ = KK*CIN;  // 832
  __shared__ __align__(16) float Bl[BSZ];
  const int tid  = threadIdx.x;
  const int node = node_base + blockIdx.x;

  for(int j = tid; j < BSZ; j += 128) Bl[j] = 0.f;

  const int e0 = row_start[node], e1 = row_start[node+1];
  const int wv   = tid >> 6;
  const int lane = tid & 63;
  const int slot = lane >> 4;
  const int c    = lane & 15;
  __syncthreads();

  if(c < CIN){
    for(int e = e0 + wv*4 + slot; e < e1; e += 8){
      const float4 q  = gw[e];
      const int4   md = gmz[e];
      const float zA = __int_as_float(md.x);
      const float zB = 1.f - zA;
      const float v  = feat[(size_t)md.w*CIN + c];
      const float vA = v*zA, vB = v*zB;
      const int cp0 = md.y, cp1 = md.z;
      lds_add(&Bl[( cp0        & 255)*CIN + c], q.x*vA);
      lds_add(&Bl[((cp0 >> 8)  & 255)*CIN + c], q.y*vA);
      lds_add(&Bl[((cp0 >> 16) & 255)*CIN + c], q.z*vA);
      lds_add(&Bl[((((unsigned)cp0) >> 24))*CIN + c], q.w*vA);
      lds_add(&Bl[( cp1        & 255)*CIN + c], q.x*vB);
      lds_add(&Bl[((cp1 >> 8)  & 255)*CIN + c], q.y*vB);
      lds_add(&Bl[((cp1 >> 16) & 255)*CIN + c], q.z*vB);
      lds_add(&Bl[((((unsigned)cp1) >> 24))*CIN + c], q.w*vB);
    }
  }
  __syncthreads();

  float* Bg = B + (size_t)blockIdx.x*BSZ;
  for(int j = tid*4; j < BSZ; j += 512)
    *(float4*)&Bg[j] = *(const float4*)&Bl[j];
}

// ---- GEMM, no atomics: P[s][node][64] = sum_{k in split s} A[row,k]*W[k,o]
__global__ __launch_bounds__(256) void k_gemm2(
    const float* __restrict__ A, const float* __restrict__ W,
    float* __restrict__ P, int M, int Kd, int node_base, int ktiles_per)
{
  __shared__ __align__(16) float As[16][68];   // [k][row]
  __shared__ __align__(16) float Ws[16][64];   // [k][col]
  const int tid = threadIdx.x;
  const int mbase = blockIdx.x * 64;
  const int s = blockIdx.y;
  const int kt0 = s * ktiles_per * 16;
  const int kt1 = min(Kd, kt0 + ktiles_per*16);
  const int ty = tid >> 4, tx = tid & 15;
  const int arow = tid >> 2, ako = (tid & 3) * 4;
  const int wk = tid >> 4,  wc = (tid & 15) * 4;

  float acc[4][4];
  #pragma unroll
  for(int i=0;i<4;++i)
    #pragma unroll
    for(int j=0;j<4;++j) acc[i][j] = 0.f;

  for(int kt = kt0; kt < kt1; kt += 16){
    float4 av = make_float4(0.f,0.f,0.f,0.f);
    const int grow = mbase + arow;
    if(grow < M) av = *(const float4*)(A + (size_t)grow*Kd + kt + ako);
    const float4 wv = *(const float4*)(W + (size_t)(kt + wk)*64 + wc);
    As[ako+0][arow]=av.x; As[ako+1][arow]=av.y; As[ako+2][arow]=av.z; As[ako+3][arow]=av.w;
    *(float4*)&Ws[wk][wc] = wv;
    __syncthreads();
    #pragma unroll
    for(int kk = 0; kk < 16; ++kk){
      const float4 a = *(const float4*)&As[kk][ty*4];
      const float4 b = *(const float4*)&Ws[kk][tx*4];
      const float aa[4] = {a.x,a.y,a.z,a.w};
      const float bb[4] = {b.x,b.y,b.z,b.w};
      #pragma unroll
      for(int i=0;i<4;++i)
        #pragma unroll
        for(int j=0;j<4;++j) acc[i][j] = fmaf(aa[i], bb[j], acc[i][j]);
    }
    __syncthreads();
  }

  #pragma unroll
  for(int i=0;i<4;++i){
    const int row = mbase + ty*4 + i;
    if(row < M)
      *(float4*)(P + ((size_t)s*NPTS + node_base + row)*64 + tx*4) = *(float4*)&acc[i][0];
  }
}

// ---- combine partials: x[node*ldout+colofs+o] += sum_s P[s][node][o]
template<int S>
__global__ void k_combine(const float* __restrict__ P, float* __restrict__ x,
                          int ldout, int colofs)
{
  int idx = blockIdx.x*blockDim.x + threadIdx.x;
  if(idx >= NPTS*16) return;
  int node = idx >> 4, c4 = (idx & 15) * 4;
  float4 s = *(const float4*)(P + (size_t)node*64 + c4);
  #pragma unroll
  for(int k=1;k<S;++k){
    float4 t = *(const float4*)(P + ((size_t)k*NPTS + node)*64 + c4);
    s.x+=t.x; s.y+=t.y; s.z+=t.z; s.w+=t.w;
  }
  float* xp = x + (size_t)node*ldout + colofs + c4;
  float4 o = *(float4*)xp;
  o.x+=s.x; o.y+=s.y; o.z+=s.z; o.w+=s.w;
  *(float4*)xp = o;
}

// ---------------- dense paths ----------------
__global__ void k_dense0(const float* __restrict__ f, const float* __restrict__ dW,
                         const float* __restrict__ db, const float* __restrict__ cb0,
                         float* __restrict__ out)
{
  int idx = blockIdx.x*blockDim.x + threadIdx.x;
  if(idx >= NPTS*96) return;
  int i = idx/96, c = idx - i*96;
  if(c < 64){ out[idx] = cb0[c]; return; }
  int o = c - 64;
  float s = db[o];
  const float* row = f + (size_t)i*13;
  #pragma unroll
  for(int j=0;j<13;++j) s = fmaf(row[j], dW[j*32+o], s);
  out[idx] = s;
}

__global__ void k_dense(const float* __restrict__ in, int cin,
                        const float* __restrict__ dW, const float* __restrict__ db,
                        const float* __restrict__ cb, const float* __restrict__ resid,
                        float* __restrict__ out)
{
  int idx = blockIdx.x*blockDim.x + threadIdx.x;
  if(idx >= NPTS*64) return;
  int i = idx >> 6, o = idx & 63;
  float s = db[o] + cb[o];
  if(resid) s += resid[idx];
  const float* row = in + (size_t)i*cin;
  for(int c=0;c<cin;++c) s = fmaf(fmaxf(row[c],0.f), dW[c*64+o], s);
  out[idx] = s;
}

__global__ void k_dense3(const float* __restrict__ x2, const float* __restrict__ dW,
                         const float* __restrict__ db, const float* __restrict__ cb,
                         float* __restrict__ out)
{
  int idx = blockIdx.x*blockDim.x + threadIdx.x;
  if(idx >= NREAL*3) return;
  int i = idx/3, o = idx - i*3;
  float s = db[o] + cb[o];
  const float* row = x2 + (size_t)i*64;
  for(int c=0;c<64;++c) s = fmaf(fmaxf(row[c],0.f), dW[c*3+o], s);
  out[idx] = s * (1.f/128.f);
}

// ---------------- host ----------------
static inline size_t alup(size_t x){ return (x + 255) & ~(size_t)255; }

static inline int calc_rows(size_t bcap, int cin, int want){
  size_t perrow = (size_t)KK * cin * 4;
  size_t r = (perrow > 0) ? bcap / perrow : 0;
  if(r >= (size_t)want) return want;
  r = (r / 128) * 128;
  if(r < 128) r = 128;
  return (int)r;
}

extern "C" void kernel_launch(void* const* d_in, const int* in_sizes, int n_in,
                              void* d_out, int out_size, void* d_ws, size_t ws_size,
                              hipStream_t stream)
{
  const float* pos   = (const float*)d_in[0];
  const float* feats = (const float*)d_in[1];
  const int*   esrc  = (const int*)d_in[2];
  const int*   edst  = (const int*)d_in[3];
  const float* c0w = (const float*)d_in[4];
  const float* c0b = (const float*)d_in[5];
  const float* d0w = (const float*)d_in[6];
  const float* d0b = (const float*)d_in[7];
  const float* c1w = (const float*)d_in[8];
  const float* c1b = (const float*)d_in[9];
  const float* d1w = (const float*)d_in[10];
  const float* d1b = (const float*)d_in[11];
  const float* c2w = (const float*)d_in[12];
  const float* c2b = (const float*)d_in[13];
  const float* d2w = (const float*)d_in[14];
  const float* d2b = (const float*)d_in[15];
  const float* c3w = (const float*)d_in[16];
  const float* c3b = (const float*)d_in[17];
  const float* d3w = (const float*)d_in[18];
  const float* d3b = (const float*)d_in[19];
  float* out = (float*)d_out;

  char* w = (char*)d_ws;
  size_t off = 0;
  float* f  = (float*)(w+off); off += alup((size_t)NPTS*13*4);
  float* x0 = (float*)(w+off); off += alup((size_t)NPTS*96*4);
  float* x1 = (float*)(w+off); off += alup((size_t)NPTS*64*4);
  float* x2 = (float*)(w+off); off += alup((size_t)NPTS*64*4);
  int* row_start = (int*)(w+off); off += alup((size_t)(NPTS+1)*4);
  int* ereal = (int*)(w+off);     off += alup(16);
  float4* gw = (float4*)(w+off);  off += alup((size_t)EPAD*16);    // per-edge xy weights
  int4*  gmz = (int4*)(w+off);    off += alup((size_t)EPAD*16);    // per-edge zA+cells+dst
  float* P  = (float*)(w+off); off += alup((size_t)8*NPTS*64*4);   // split-K partials (S<=8)
  float* B = (float*)(w+off);
  size_t bcap = (ws_size > off) ? (ws_size - off) : 0;

  k_find_ereal<<<1,1,0,stream>>>(edst, ereal);
  k_csr<<<(NPTS+1+255)/256,256,0,stream>>>(esrc, ereal, row_start);
  k_build_f<<<(NPTS*13+255)/256,256,0,stream>>>(feats, f);
  k_geom<<<(EPAD+255)/256,256,0,stream>>>(pos, esrc, edst, gw, gmz);

  // ---- layer 0: x0[:,0:64] = cconv0(f)+c0b ; x0[:,64:96] = f@d0w+d0b  (chunk 8192)
  k_dense0<<<(NPTS*96+255)/256,256,0,stream>>>(f, d0w, d0b, c0b, x0);
  {
    int rows = calc_rows(bcap, 13, 8192);
    for(int base = 0; base < NPTS; base += rows){
      int m = (NPTS - base < rows) ? (NPTS - base) : rows;
      k_scat13<<<m,128,0,stream>>>(f, gw, gmz, row_start, B, base);
      k_gemm2<<<dim3((m+63)/64, 8),256,0,stream>>>(B, c0w, P, m, 832, base, 7);
    }
    k_combine<8><<<(NPTS*16+255)/256,256,0,stream>>>(P, x0, 96, 0);
  }

  // ---- layer 1: x1 = cconv1(relu(x0)) + relu(x0)@d1w + d1b + c1b   (chunk 4096)
  k_dense<<<(NPTS*64+255)/256,256,0,stream>>>(x0, 96, d1w, d1b, c1b, nullptr, x1);
  {
    int rows = calc_rows(bcap, 96, 4096);
    for(int base = 0; base < NPTS; base += rows){
      int m = (NPTS - base < rows) ? (NPTS - base) : rows;
      k_scat96<1><<<m,128,0,stream>>>(x0, gw, gmz, row_start, B, base);
      k_gemm2<<<dim3((m+63)/64, 8),256,0,stream>>>(B, c1w, P, m, 6144, base, 48);
    }
    k_combine<8><<<(NPTS*16+255)/256,256,0,stream>>>(P, x1, 64, 0);
  }

  // ---- layer 2: x2 = cconv2(relu(x1)) + relu(x1)@d2w + d2b + c2b + x1  (chunk 4096)
  k_dense<<<(NPTS*64+255)/256,256,0,stream>>>(x1, 64, d2w, d2b, c2b, x1, x2);
  {
    int rows = calc_rows(bcap, 64, 4096);
    for(int base = 0; base < NPTS; base += rows){
      int m = (NPTS - base < rows) ? (NPTS - base) : rows;
      k_scat64<1,0><<<m,128,0,stream>>>(x1, gw, gmz, row_start, B, base, nullptr, nullptr);
      k_gemm2<<<dim3((m+63)/64, 8),256,0,stream>>>(B, c2w, P, m, 4096, base, 32);
    }
    k_combine<8><<<(NPTS*16+255)/256,256,0,stream>>>(P, x2, 64, 0);
  }

  // ---- layer 3 (fused): out = dense3 part, then scatter adds conv3 GEMV directly
  k_dense3<<<(NREAL*3+255)/256,256,0,stream>>>(x2, d3w, d3b, c3b, out);
  k_scat64<1,1><<<NPTS,128,0,stream>>>(x2, gw, gmz, row_start, nullptr, 0, c3w, out);
}

// Round 3
// 1424.581 us; speedup vs baseline: 6.5795x; 6.5795x over previous
//
#include <hip/hip_runtime.h>
#include <math.h>

#define NPTS   20001
#define NREAL  20000
#define EPAD   1200000
#define KK     64
#define RADF   0.1125f

__device__ __forceinline__ float sgnf(float v){ return v>0.f ? 1.f : (v<0.f ? -1.f : 0.f); }

// ---------------- CSR build (edge_src is sorted; pad edges have dst==NREAL) ----------------
__global__ void k_find_ereal(const int* __restrict__ dst, int* __restrict__ ereal){
  int lo=0, hi=EPAD;
  while(lo<hi){ int mid=(lo+hi)>>1; if(dst[mid]==NREAL) hi=mid; else lo=mid+1; }
  *ereal = lo;
}

__global__ void k_csr(const int* __restrict__ src, const int* __restrict__ erealp,
                      int* __restrict__ row_start){
  int i = blockIdx.x*blockDim.x + threadIdx.x;
  if(i > NPTS) return;
  int E = *erealp;
  int lo=0, hi=E;
  while(lo<hi){ int mid=(lo+hi)>>1; if(src[mid] < i) lo=mid+1; else hi=mid; }
  row_start[i] = lo;
}

__global__ void k_build_f(const float* __restrict__ feats, float* __restrict__ f){
  int idx = blockIdx.x*blockDim.x + threadIdx.x;
  if(idx >= NPTS*13) return;
  int i = idx/13, c = idx - i*13;
  f[idx] = (c==0) ? 1.f : feats[i*12 + (c-1)];
}

// ---------------- per-edge geometry (exact port of ball_to_cube + window) ----------------
__device__ __forceinline__ void edge_geom(float ox, float oy, float oz,
                                          float& win, float& t0, float& t1, float& t2, int& f0p){
  const float eps = 1e-9f;
  float sq = ox*ox + oy*oy + oz*oz;
  float u = 1.f - sq;
  win = fminf(fmaxf(u*u*u, 0.f), 1.f);
  float norm = sqrtf(sq + eps);
  float rxy2 = ox*ox + oy*oy;
  bool polar = (1.25f*oz*oz > rxy2);
  float s_p = sqrtf(3.f*norm/(norm + fabsf(oz) + eps));
  float s_n = norm / sqrtf(rxy2 + eps);
  float s = polar ? s_p : s_n;
  float xc = ox*s, yc = oy*s;
  float zc = polar ? sgnf(oz)*norm : 1.5f*oz;
  if(sq < 1e-12f){ xc = 0.f; yc = 0.f; zc = 0.f; }
  float r = sqrtf(xc*xc + yc*yc + eps);
  bool c1 = fabsf(xc) >= fabsf(yc);
  float xs = (fabsf(xc) < eps) ? eps : xc;
  float ys = (fabsf(yc) < eps) ? eps : yc;
  const float fop = 1.2732395447351628f; // float32(4/pi)
  float a = c1 ? sgnf(xc)*r : sgnf(yc)*r*fop*atanf(xc/ys);
  float b = c1 ? sgnf(xc)*r*fop*atanf(yc/xs) : sgnf(yc)*r;
  if(xc*xc + yc*yc < 1e-12f){ a = 0.f; b = 0.f; }
  float g0 = fminf(fmaxf((a *0.5f+0.5f)*3.f, 0.f), 3.f);
  float g1 = fminf(fmaxf((b *0.5f+0.5f)*3.f, 0.f), 3.f);
  float g2 = fminf(fmaxf((zc*0.5f+0.5f)*3.f, 0.f), 3.f);
  float f00 = floorf(g0), f01 = floorf(g1), f02 = floorf(g2);
  t0 = g0 - f00; t1 = g1 - f01; t2 = g2 - f02;
  f0p = (int)f00 | ((int)f01 << 2) | ((int)f02 << 4);
}

// ---- k_geom: per-edge staged data, computed ONCE (shared by all 4 scatter layers).
// gw[e]  = win-premultiplied xy-quad weights {q00,q01,q10,q11}
// gmz[e] = {bits(zA), cells0, cells1, dst}; zB = 1-zA (wz0+wz1==1 exactly).
// min(i+1,3) -> (i+1)&3 is exact (clamped corner has t==0 weight): all 8 cells distinct ->
// batched read/fma/write in the scatters is race-free; parity-p cells owned by wave p.
__global__ __launch_bounds__(256) void k_geom(const float* __restrict__ pos,
    const int* __restrict__ esrc, const int* __restrict__ edst,
    float4* __restrict__ gw, int4* __restrict__ gmz)
{
  int e = blockIdx.x*blockDim.x + threadIdx.x;
  if(e >= EPAD) return;
  const int sn = esrc[e], d = edst[e];
  const float ox = (pos[d*3+0]-pos[sn*3+0])/RADF;
  const float oy = (pos[d*3+1]-pos[sn*3+1])/RADF;
  const float oz = (pos[d*3+2]-pos[sn*3+2])/RADF;
  float win, t0, t1, t2; int f0p;
  edge_geom(ox, oy, oz, win, t0, t1, t2, f0p);
  const int i0 = f0p & 3, i1 = (f0p>>2) & 3, i2 = f0p >> 4;
  const int X0 = i0 << 4, X1 = ((i0+1)&3) << 4;
  const int Y0 = i1 << 2, Y1 = ((i1+1)&3) << 2;
  const int Z0 = i2, Z1 = (i2+1) & 3;
  const float wx0 = win*(1.f-t0), wx1 = win*t0;
  const float wy0 = 1.f-t1, wy1 = t1;
  const float wz0 = 1.f-t2, wz1 = t2;
  gw[e] = make_float4(wx0*wy0, wx0*wy1, wx1*wy0, wx1*wy1);
  const int p0 = Z0 & 1;
  const float zA = p0 ? wz1 : wz0;                  // weight for parity-0 (even z) cell
  const int   cA = p0 ? Z1 : Z0;                    // even-z cell
  const int   cB = p0 ? Z0 : Z1;                    // odd-z cell
  const int cells0 = (X0|Y0|cA) | ((X0|Y1|cA)<<8) | ((X1|Y0|cA)<<16) | ((X1|Y1|cA)<<24);
  const int cells1 = (X0|Y0|cB) | ((X0|Y1|cB)<<8) | ((X1|Y0|cB)<<16) | ((X1|Y1|cB)<<24);
  gmz[e] = make_int4(__float_as_int(zA), cells0, cells1, d);
}

// ------- scatter CIN=64: 2 waves (z-parity cells), b64 RMW: each lane owns 2 channels
// (float2, m=lane&31), lane-half h=lane>>5 owns cell {c0,c1} / {c2,c3} of the wave's 4.
// 8 wave-LDS-ops/edge (4 b64 per wave) vs 16 b32 in the round-1 form. Race-free: all 8
// cells distinct; halves and sequential pair-ops touch distinct cells; waves z-disjoint.
// OUT3=1: fused cout=3 GEMV epilogue (layer 3).
template<int RELU, int OUT3>
__global__ __launch_bounds__(128) void k_scat64(
    const float* __restrict__ feat, const float4* __restrict__ gw,
    const int4* __restrict__ gmz, const int* __restrict__ row_start,
    float* __restrict__ B, int node_base,
    const float* __restrict__ W3, float* __restrict__ out)
{
  constexpr int BSZ = 64*64;
  __shared__ __align__(16) float Bl[BSZ];
  __shared__ float red[OUT3 ? 384 : 4];
  const int tid  = threadIdx.x;
  const int node = node_base + blockIdx.x;

  for(int j = tid*4; j < BSZ; j += 512)
    *(float4*)&Bl[j] = make_float4(0.f,0.f,0.f,0.f);

  const int e0 = row_start[node], e1 = row_start[node+1];
  const int wv = tid >> 6;          // z-parity owned by this wave
  const int h  = (tid >> 5) & 1;    // lane-half: which cell of each pair
  const int m  = tid & 31;          // owned channel pair (ch 2m, 2m+1)
  float2* Bp2 = (float2*)Bl;
  const float2* feat2 = (const float2*)feat;
  __syncthreads();

  #pragma unroll 2
  for(int e = e0; e < e1; ++e){
    const float4 q  = gw[e];
    const int4   md = gmz[e];
    const float zA = __int_as_float(md.x);
    const float z  = wv ? (1.f - zA) : zA;
    const int   cp = wv ? md.z : md.y;
    float2 v2 = feat2[(size_t)md.w*32 + m];
    if(RELU){ v2.x = fmaxf(v2.x, 0.f); v2.y = fmaxf(v2.y, 0.f); }
    v2.x *= z; v2.y *= z;
    // pair 1: cells c0 (q.x) / c1 (q.y); pair 2: cells c2 (q.z) / c3 (q.w)
    const int   cA = h ? ((cp >> 8)  & 255) : ( cp        & 255);
    const int   cB = h ? ((int)(((unsigned)cp) >> 24)) : ((cp >> 16) & 255);
    const float qA = h ? q.y : q.x;
    const float qB = h ? q.w : q.z;
    const int a1 = (cA << 5) + m;
    const int a2 = (cB << 5) + m;
    float2 o1 = Bp2[a1];
    o1.x = fmaf(qA, v2.x, o1.x); o1.y = fmaf(qA, v2.y, o1.y);
    Bp2[a1] = o1;
    float2 o2 = Bp2[a2];
    o2.x = fmaf(qB, v2.x, o2.x); o2.y = fmaf(qB, v2.y, o2.y);
    Bp2[a2] = o2;
  }
  __syncthreads();

  if(!OUT3){
    float* Bg = B + (size_t)blockIdx.x*BSZ;
    for(int j = tid*4; j < BSZ; j += 512)
      *(float4*)&Bg[j] = *(const float4*)&Bl[j];
  } else {
    float s0=0.f, s1=0.f, s2=0.f;
    for(int j = tid; j < BSZ; j += 128){
      float v = Bl[j];
      s0 = fmaf(v, W3[j*3+0], s0);
      s1 = fmaf(v, W3[j*3+1], s1);
      s2 = fmaf(v, W3[j*3+2], s2);
    }
    float* r0 = red; float* r1 = red+128; float* r2 = red+256;
    r0[tid]=s0; r1[tid]=s1; r2[tid]=s2;
    __syncthreads();
    for(int st = 64; st > 0; st >>= 1){
      if(tid < st){ r0[tid]+=r0[tid+st]; r1[tid]+=r1[tid+st]; r2[tid]+=r2[tid+st]; }
      __syncthreads();
    }
    if(tid == 0 && node < NREAL){
      out[node*3+0] += r0[0]*(1.f/128.f);
      out[node*3+1] += r1[0]*(1.f/128.f);
      out[node*3+2] += r2[0]*(1.f/128.f);
    }
  }
}

// ------- scatter CIN=96: float2 channel pairs (48 lanes), z-parity waves, barrier-free ----
template<int RELU>
__global__ __launch_bounds__(128) void k_scat96(
    const float* __restrict__ feat, const float4* __restrict__ gw,
    const int4* __restrict__ gmz, const int* __restrict__ row_start,
    float* __restrict__ B, int node_base)
{
  constexpr int CIN = 96, BSZ = KK*CIN, NP = 48;
  __shared__ __align__(16) float Bl[BSZ];
  const int tid  = threadIdx.x;
  const int node = node_base + blockIdx.x;

  for(int j = tid*4; j < BSZ; j += 512)
    *(float4*)&Bl[j] = make_float4(0.f,0.f,0.f,0.f);

  const int e0 = row_start[node], e1 = row_start[node+1];
  const int wv   = tid >> 6;
  const int lane = tid & 63;
  const bool act = (lane < NP);
  float2* Bp2 = (float2*)Bl;
  __syncthreads();

  if(act){
    #pragma unroll 2
    for(int e = e0; e < e1; ++e){
      const float4 q  = gw[e];
      const int4   md = gmz[e];
      const float zA = __int_as_float(md.x);
      const float z  = wv ? (1.f - zA) : zA;
      const int   cp = wv ? md.z : md.y;
      float2 v2 = ((const float2*)(feat + (size_t)md.w*CIN))[lane];
      if(RELU){ v2.x = fmaxf(v2.x,0.f); v2.y = fmaxf(v2.y,0.f); }
      v2.x *= z; v2.y *= z;
      const int b0 = ( cp        & 255)*NP + lane;
      const int b1 = ((cp >> 8)  & 255)*NP + lane;
      const int b2 = ((cp >> 16) & 255)*NP + lane;
      const int b3 = (((unsigned)cp) >> 24)*NP + lane;
      float2 o0 = Bp2[b0], o1 = Bp2[b1], o2 = Bp2[b2], o3 = Bp2[b3];
      o0.x = fmaf(q.x, v2.x, o0.x); o0.y = fmaf(q.x, v2.y, o0.y);
      o1.x = fmaf(q.y, v2.x, o1.x); o1.y = fmaf(q.y, v2.y, o1.y);
      o2.x = fmaf(q.z, v2.x, o2.x); o2.y = fmaf(q.z, v2.y, o2.y);
      o3.x = fmaf(q.w, v2.x, o3.x); o3.y = fmaf(q.w, v2.y, o3.y);
      Bp2[b0] = o0; Bp2[b1] = o1; Bp2[b2] = o2; Bp2[b3] = o3;
    }
  }
  __syncthreads();

  float* Bg = B + (size_t)blockIdx.x*BSZ;
  for(int j = tid*4; j < BSZ; j += 512)
    *(float4*)&Bg[j] = *(const float4*)&Bl[j];
}

// ------- scatter CIN=13: 4 edge-slots/wave (slot-private copies), z-parity waves ----------
__global__ __launch_bounds__(128) void k_scat13(
    const float* __restrict__ feat, const float4* __restrict__ gw,
    const int4* __restrict__ gmz, const int* __restrict__ row_start,
    float* __restrict__ B, int node_base)
{
  constexpr int CIN = 13, BSZ = KK*CIN, ESW = 4, CSTRIDE = BSZ + 8;
  __shared__ __align__(16) float Bl[ESW*CSTRIDE];
  const int tid  = threadIdx.x;
  const int node = node_base + blockIdx.x;

  for(int j = tid; j < ESW*CSTRIDE; j += 128) Bl[j] = 0.f;

  const int e0 = row_start[node], e1 = row_start[node+1];
  const int wv   = tid >> 6;
  const int lane = tid & 63;
  const int slot = lane >> 4;
  const int c    = lane & 15;
  const bool act = (c < CIN);
  float* Bp = Bl + slot*CSTRIDE;
  __syncthreads();

  if(act){
    for(int e = e0 + slot; e < e1; e += ESW){
      const float4 q  = gw[e];
      const int4   md = gmz[e];
      const float zA = __int_as_float(md.x);
      const float z  = wv ? (1.f - zA) : zA;
      const int   cp = wv ? md.z : md.y;
      float v = feat[(size_t)md.w*CIN + c] * z;
      const int b0 = ( cp        & 255)*CIN + c;
      const int b1 = ((cp >> 8)  & 255)*CIN + c;
      const int b2 = ((cp >> 16) & 255)*CIN + c;
      const int b3 = (((unsigned)cp) >> 24)*CIN + c;
      float o0 = Bp[b0], o1 = Bp[b1], o2 = Bp[b2], o3 = Bp[b3];
      o0 = fmaf(q.x, v, o0); o1 = fmaf(q.y, v, o1);
      o2 = fmaf(q.z, v, o2); o3 = fmaf(q.w, v, o3);
      Bp[b0] = o0; Bp[b1] = o1; Bp[b2] = o2; Bp[b3] = o3;
    }
  }
  __syncthreads();

  float* Bg = B + (size_t)blockIdx.x*BSZ;
  for(int j = tid*4; j < BSZ; j += 512){
    float4 a = *(const float4*)&Bl[j];
    #pragma unroll
    for(int k = 1; k < ESW; ++k){
      const float4 t = *(const float4*)&Bl[k*CSTRIDE + j];
      a.x += t.x; a.y += t.y; a.z += t.z; a.w += t.w;
    }
    *(float4*)&Bg[j] = a;
  }
}

// ---- GEMM, no atomics: P[s][node][64] = sum_{k in split s} A[row,k]*W[k,o]
__global__ __launch_bounds__(256) void k_gemm2(
    const float* __restrict__ A, const float* __restrict__ W,
    float* __restrict__ P, int M, int Kd, int node_base, int ktiles_per)
{
  __shared__ __align__(16) float As[16][68];   // [k][row]
  __shared__ __align__(16) float Ws[16][64];   // [k][col]
  const int tid = threadIdx.x;
  const int mbase = blockIdx.x * 64;
  const int s = blockIdx.y;
  const int kt0 = s * ktiles_per * 16;
  const int kt1 = min(Kd, kt0 + ktiles_per*16);
  const int ty = tid >> 4, tx = tid & 15;
  const int arow = tid >> 2, ako = (tid & 3) * 4;
  const int wk = tid >> 4,  wc = (tid & 15) * 4;

  float acc[4][4];
  #pragma unroll
  for(int i=0;i<4;++i)
    #pragma unroll
    for(int j=0;j<4;++j) acc[i][j] = 0.f;

  for(int kt = kt0; kt < kt1; kt += 16){
    float4 av = make_float4(0.f,0.f,0.f,0.f);
    const int grow = mbase + arow;
    if(grow < M) av = *(const float4*)(A + (size_t)grow*Kd + kt + ako);
    const float4 wv = *(const float4*)(W + (size_t)(kt + wk)*64 + wc);
    As[ako+0][arow]=av.x; As[ako+1][arow]=av.y; As[ako+2][arow]=av.z; As[ako+3][arow]=av.w;
    *(float4*)&Ws[wk][wc] = wv;
    __syncthreads();
    #pragma unroll
    for(int kk = 0; kk < 16; ++kk){
      const float4 a = *(const float4*)&As[kk][ty*4];
      const float4 b = *(const float4*)&Ws[kk][tx*4];
      const float aa[4] = {a.x,a.y,a.z,a.w};
      const float bb[4] = {b.x,b.y,b.z,b.w};
      #pragma unroll
      for(int i=0;i<4;++i)
        #pragma unroll
        for(int j=0;j<4;++j) acc[i][j] = fmaf(aa[i], bb[j], acc[i][j]);
    }
    __syncthreads();
  }

  #pragma unroll
  for(int i=0;i<4;++i){
    const int row = mbase + ty*4 + i;
    if(row < M)
      *(float4*)(P + ((size_t)s*NPTS + node_base + row)*64 + tx*4) = *(float4*)&acc[i][0];
  }
}

// ---- combine partials: x[node*ldout+colofs+o] += sum_s P[s][node][o]
template<int S>
__global__ void k_combine(const float* __restrict__ P, float* __restrict__ x,
                          int ldout, int colofs)
{
  int idx = blockIdx.x*blockDim.x + threadIdx.x;
  if(idx >= NPTS*16) return;
  int node = idx >> 4, c4 = (idx & 15) * 4;
  float4 s = *(const float4*)(P + (size_t)node*64 + c4);
  #pragma unroll
  for(int k=1;k<S;++k){
    float4 t = *(const float4*)(P + ((size_t)k*NPTS + node)*64 + c4);
    s.x+=t.x; s.y+=t.y; s.z+=t.z; s.w+=t.w;
  }
  float* xp = x + (size_t)node*ldout + colofs + c4;
  float4 o = *(float4*)xp;
  o.x+=s.x; o.y+=s.y; o.z+=s.z; o.w+=s.w;
  *(float4*)xp = o;
}

// ---------------- dense paths ----------------
__global__ void k_dense0(const float* __restrict__ f, const float* __restrict__ dW,
                         const float* __restrict__ db, const float* __restrict__ cb0,
                         float* __restrict__ out)
{
  int idx = blockIdx.x*blockDim.x + threadIdx.x;
  if(idx >= NPTS*96) return;
  int i = idx/96, c = idx - i*96;
  if(c < 64){ out[idx] = cb0[c]; return; }
  int o = c - 64;
  float s = db[o];
  const float* row = f + (size_t)i*13;
  #pragma unroll
  for(int j=0;j<13;++j) s = fmaf(row[j], dW[j*32+o], s);
  out[idx] = s;
}

__global__ void k_dense(const float* __restrict__ in, int cin,
                        const float* __restrict__ dW, const float* __restrict__ db,
                        const float* __restrict__ cb, const float* __restrict__ resid,
                        float* __restrict__ out)
{
  int idx = blockIdx.x*blockDim.x + threadIdx.x;
  if(idx >= NPTS*64) return;
  int i = idx >> 6, o = idx & 63;
  float s = db[o] + cb[o];
  if(resid) s += resid[idx];
  const float* row = in + (size_t)i*cin;
  for(int c=0;c<cin;++c) s = fmaf(fmaxf(row[c],0.f), dW[c*64+o], s);
  out[idx] = s;
}

__global__ void k_dense3(const float* __restrict__ x2, const float* __restrict__ dW,
                         const float* __restrict__ db, const float* __restrict__ cb,
                         float* __restrict__ out)
{
  int idx = blockIdx.x*blockDim.x + threadIdx.x;
  if(idx >= NREAL*3) return;
  int i = idx/3, o = idx - i*3;
  float s = db[o] + cb[o];
  const float* row = x2 + (size_t)i*64;
  for(int c=0;c<64;++c) s = fmaf(fmaxf(row[c],0.f), dW[c*3+o], s);
  out[idx] = s * (1.f/128.f);
}

// ---------------- host ----------------
static inline size_t alup(size_t x){ return (x + 255) & ~(size_t)255; }

static inline int calc_rows(size_t bcap, int cin, int want){
  size_t perrow = (size_t)KK * cin * 4;
  size_t r = (perrow > 0) ? bcap / perrow : 0;
  if(r >= (size_t)want) return want;
  r = (r / 128) * 128;
  if(r < 128) r = 128;
  return (int)r;
}

extern "C" void kernel_launch(void* const* d_in, const int* in_sizes, int n_in,
                              void* d_out, int out_size, void* d_ws, size_t ws_size,
                              hipStream_t stream)
{
  const float* pos   = (const float*)d_in[0];
  const float* feats = (const float*)d_in[1];
  const int*   esrc  = (const int*)d_in[2];
  const int*   edst  = (const int*)d_in[3];
  const float* c0w = (const float*)d_in[4];
  const float* c0b = (const float*)d_in[5];
  const float* d0w = (const float*)d_in[6];
  const float* d0b = (const float*)d_in[7];
  const float* c1w = (const float*)d_in[8];
  const float* c1b = (const float*)d_in[9];
  const float* d1w = (const float*)d_in[10];
  const float* d1b = (const float*)d_in[11];
  const float* c2w = (const float*)d_in[12];
  const float* c2b = (const float*)d_in[13];
  const float* d2w = (const float*)d_in[14];
  const float* d2b = (const float*)d_in[15];
  const float* c3w = (const float*)d_in[16];
  const float* c3b = (const float*)d_in[17];
  const float* d3w = (const float*)d_in[18];
  const float* d3b = (const float*)d_in[19];
  float* out = (float*)d_out;

  char* w = (char*)d_ws;
  size_t off = 0;
  float* f  = (float*)(w+off); off += alup((size_t)NPTS*13*4);
  float* x0 = (float*)(w+off); off += alup((size_t)NPTS*96*4);
  float* x1 = (float*)(w+off); off += alup((size_t)NPTS*64*4);
  float* x2 = (float*)(w+off); off += alup((size_t)NPTS*64*4);
  int* row_start = (int*)(w+off); off += alup((size_t)(NPTS+1)*4);
  int* ereal = (int*)(w+off);     off += alup(16);
  float4* gw = (float4*)(w+off);  off += alup((size_t)EPAD*16);    // per-edge xy weights
  int4*  gmz = (int4*)(w+off);    off += alup((size_t)EPAD*16);    // per-edge zA+cells+dst
  float* P  = (float*)(w+off); off += alup((size_t)8*NPTS*64*4);   // split-K partials (S<=8)
  float* B = (float*)(w+off);
  size_t bcap = (ws_size > off) ? (ws_size - off) : 0;

  k_find_ereal<<<1,1,0,stream>>>(edst, ereal);
  k_csr<<<(NPTS+1+255)/256,256,0,stream>>>(esrc, ereal, row_start);
  k_build_f<<<(NPTS*13+255)/256,256,0,stream>>>(feats, f);
  k_geom<<<(EPAD+255)/256,256,0,stream>>>(pos, esrc, edst, gw, gmz);

  // ---- layer 0: x0[:,0:64] = cconv0(f)+c0b ; x0[:,64:96] = f@d0w+d0b  (chunk 8192)
  k_dense0<<<(NPTS*96+255)/256,256,0,stream>>>(f, d0w, d0b, c0b, x0);
  {
    int rows = calc_rows(bcap, 13, 8192);
    for(int base = 0; base < NPTS; base += rows){
      int m = (NPTS - base < rows) ? (NPTS - base) : rows;
      k_scat13<<<m,128,0,stream>>>(f, gw, gmz, row_start, B, base);
      k_gemm2<<<dim3((m+63)/64, 8),256,0,stream>>>(B, c0w, P, m, 832, base, 7);
    }
    k_combine<8><<<(NPTS*16+255)/256,256,0,stream>>>(P, x0, 96, 0);
  }

  // ---- layer 1: x1 = cconv1(relu(x0)) + relu(x0)@d1w + d1b + c1b   (chunk 4096)
  k_dense<<<(NPTS*64+255)/256,256,0,stream>>>(x0, 96, d1w, d1b, c1b, nullptr, x1);
  {
    int rows = calc_rows(bcap, 96, 4096);
    for(int base = 0; base < NPTS; base += rows){
      int m = (NPTS - base < rows) ? (NPTS - base) : rows;
      k_scat96<1><<<m,128,0,stream>>>(x0, gw, gmz, row_start, B, base);
      k_gemm2<<<dim3((m+63)/64, 8),256,0,stream>>>(B, c1w, P, m, 6144, base, 48);
    }
    k_combine<8><<<(NPTS*16+255)/256,256,0,stream>>>(P, x1, 64, 0);
  }

  // ---- layer 2: x2 = cconv2(relu(x1)) + relu(x1)@d2w + d2b + c2b + x1  (chunk 4096)
  k_dense<<<(NPTS*64+255)/256,256,0,stream>>>(x1, 64, d2w, d2b, c2b, x1, x2);
  {
    int rows = calc_rows(bcap, 64, 4096);
    for(int base = 0; base < NPTS; base += rows){
      int m = (NPTS - base < rows) ? (NPTS - base) : rows;
      k_scat64<1,0><<<m,128,0,stream>>>(x1, gw, gmz, row_start, B, base, nullptr, nullptr);
      k_gemm2<<<dim3((m+63)/64, 8),256,0,stream>>>(B, c2w, P, m, 4096, base, 32);
    }
    k_combine<8><<<(NPTS*16+255)/256,256,0,stream>>>(P, x2, 64, 0);
  }

  // ---- layer 3 (fused): out = dense3 part, then scatter adds conv3 GEMV directly
  k_dense3<<<(NREAL*3+255)/256,256,0,stream>>>(x2, d3w, d3b, c3b, out);
  k_scat64<1,1><<<NPTS,128,0,stream>>>(x2, gw, gmz, row_start, nullptr, 0, c3w, out);
}

// Round 4
// 1390.589 us; speedup vs baseline: 6.7404x; 1.0244x over previous
//
#include <hip/hip_runtime.h>
#include <math.h>

#define NPTS   20001
#define NREAL  20000
#define EPAD   1200000
#define KK     64
#define RADF   0.1125f

__device__ __forceinline__ float sgnf(float v){ return v>0.f ? 1.f : (v<0.f ? -1.f : 0.f); }

// ---------------- CSR build (edge_src is sorted; pad edges have dst==NREAL) ----------------
__global__ void k_find_ereal(const int* __restrict__ dst, int* __restrict__ ereal){
  int lo=0, hi=EPAD;
  while(lo<hi){ int mid=(lo+hi)>>1; if(dst[mid]==NREAL) hi=mid; else lo=mid+1; }
  *ereal = lo;
}

__global__ void k_csr(const int* __restrict__ src, const int* __restrict__ erealp,
                      int* __restrict__ row_start){
  int i = blockIdx.x*blockDim.x + threadIdx.x;
  if(i > NPTS) return;
  int E = *erealp;
  int lo=0, hi=E;
  while(lo<hi){ int mid=(lo+hi)>>1; if(src[mid] < i) lo=mid+1; else hi=mid; }
  row_start[i] = lo;
}

__global__ void k_build_f(const float* __restrict__ feats, float* __restrict__ f){
  int idx = blockIdx.x*blockDim.x + threadIdx.x;
  if(idx >= NPTS*13) return;
  int i = idx/13, c = idx - i*13;
  f[idx] = (c==0) ? 1.f : feats[i*12 + (c-1)];
}

// ---------------- per-edge geometry (exact port of ball_to_cube + window) ----------------
__device__ __forceinline__ void edge_geom(float ox, float oy, float oz,
                                          float& win, float& t0, float& t1, float& t2, int& f0p){
  const float eps = 1e-9f;
  float sq = ox*ox + oy*oy + oz*oz;
  float u = 1.f - sq;
  win = fminf(fmaxf(u*u*u, 0.f), 1.f);
  float norm = sqrtf(sq + eps);
  float rxy2 = ox*ox + oy*oy;
  bool polar = (1.25f*oz*oz > rxy2);
  float s_p = sqrtf(3.f*norm/(norm + fabsf(oz) + eps));
  float s_n = norm / sqrtf(rxy2 + eps);
  float s = polar ? s_p : s_n;
  float xc = ox*s, yc = oy*s;
  float zc = polar ? sgnf(oz)*norm : 1.5f*oz;
  if(sq < 1e-12f){ xc = 0.f; yc = 0.f; zc = 0.f; }
  float r = sqrtf(xc*xc + yc*yc + eps);
  bool c1 = fabsf(xc) >= fabsf(yc);
  float xs = (fabsf(xc) < eps) ? eps : xc;
  float ys = (fabsf(yc) < eps) ? eps : yc;
  const float fop = 1.2732395447351628f; // float32(4/pi)
  float a = c1 ? sgnf(xc)*r : sgnf(yc)*r*fop*atanf(xc/ys);
  float b = c1 ? sgnf(xc)*r*fop*atanf(yc/xs) : sgnf(yc)*r;
  if(xc*xc + yc*yc < 1e-12f){ a = 0.f; b = 0.f; }
  float g0 = fminf(fmaxf((a *0.5f+0.5f)*3.f, 0.f), 3.f);
  float g1 = fminf(fmaxf((b *0.5f+0.5f)*3.f, 0.f), 3.f);
  float g2 = fminf(fmaxf((zc*0.5f+0.5f)*3.f, 0.f), 3.f);
  float f00 = floorf(g0), f01 = floorf(g1), f02 = floorf(g2);
  t0 = g0 - f00; t1 = g1 - f01; t2 = g2 - f02;
  f0p = (int)f00 | ((int)f01 << 2) | ((int)f02 << 4);
}

// ---- k_geom: per-edge staged data, computed ONCE (shared by all 4 scatter layers).
// gw[e]  = win-premultiplied xy-quad weights {q00,q01,q10,q11}
// gmz[e] = {bits(zA), cells0, cells1, dst}; zB = 1-zA (wz0+wz1==1 exactly).
// min(i+1,3) -> (i+1)&3 is exact (clamped corner has t==0 weight): all 8 cells distinct ->
// batched read/fma/write in the scatters is race-free; parity-p cells owned by wave p.
__global__ __launch_bounds__(256) void k_geom(const float* __restrict__ pos,
    const int* __restrict__ esrc, const int* __restrict__ edst,
    float4* __restrict__ gw, int4* __restrict__ gmz)
{
  int e = blockIdx.x*blockDim.x + threadIdx.x;
  if(e >= EPAD) return;
  const int sn = esrc[e], d = edst[e];
  const float ox = (pos[d*3+0]-pos[sn*3+0])/RADF;
  const float oy = (pos[d*3+1]-pos[sn*3+1])/RADF;
  const float oz = (pos[d*3+2]-pos[sn*3+2])/RADF;
  float win, t0, t1, t2; int f0p;
  edge_geom(ox, oy, oz, win, t0, t1, t2, f0p);
  const int i0 = f0p & 3, i1 = (f0p>>2) & 3, i2 = f0p >> 4;
  const int X0 = i0 << 4, X1 = ((i0+1)&3) << 4;
  const int Y0 = i1 << 2, Y1 = ((i1+1)&3) << 2;
  const int Z0 = i2, Z1 = (i2+1) & 3;
  const float wx0 = win*(1.f-t0), wx1 = win*t0;
  const float wy0 = 1.f-t1, wy1 = t1;
  const float wz0 = 1.f-t2, wz1 = t2;
  gw[e] = make_float4(wx0*wy0, wx0*wy1, wx1*wy0, wx1*wy1);
  const int p0 = Z0 & 1;
  const float zA = p0 ? wz1 : wz0;                  // weight for parity-0 (even z) cell
  const int   cA = p0 ? Z1 : Z0;                    // even-z cell
  const int   cB = p0 ? Z0 : Z1;                    // odd-z cell
  const int cells0 = (X0|Y0|cA) | ((X0|Y1|cA)<<8) | ((X1|Y0|cA)<<16) | ((X1|Y1|cA)<<24);
  const int cells1 = (X0|Y0|cB) | ((X0|Y1|cB)<<8) | ((X1|Y0|cB)<<16) | ((X1|Y1|cB)<<24);
  gmz[e] = make_int4(__float_as_int(zA), cells0, cells1, d);
}

// ------- scatter CIN=64: 2 waves (z-parity cells), float4 (b128) RMW.
// Lane layout: g=(tid>>4)&3 -> which of this wave's 4 cells; f=tid&15 -> channel quad
// (ch 4f..4f+3). Per edge per wave: 1 ds_read_b128 + 4 fma + 1 ds_write_b128.
// Same 4KB LDS traffic/edge as the b32 form but moved at b128 byte-rate (~85 vs ~44 B/cyc,
// m134). Race-free: 4 cells of a wave all distinct (X0!=X1, Y0!=Y1), waves z-parity
// disjoint, lanes own disjoint channel quads. Bank-minimal: wave access = 1KB = 8 words/bank.
// OUT3=1: fused cout=3 GEMV epilogue (layer 3), shfl-based reduce (tiny red[] -> 9 blk/CU).
template<int RELU, int OUT3>
__global__ __launch_bounds__(128) void k_scat64(
    const float* __restrict__ feat, const float4* __restrict__ gw,
    const int4* __restrict__ gmz, const int* __restrict__ row_start,
    float* __restrict__ B, int node_base,
    const float* __restrict__ W3, float* __restrict__ out)
{
  constexpr int BSZ = 64*64;
  __shared__ __align__(16) float Bl[BSZ];
  __shared__ float red[8];
  const int tid  = threadIdx.x;
  const int node = node_base + blockIdx.x;

  for(int j = tid*4; j < BSZ; j += 512)
    *(float4*)&Bl[j] = make_float4(0.f,0.f,0.f,0.f);

  const int e0 = row_start[node], e1 = row_start[node+1];
  const int wv  = tid >> 6;         // z-parity owned by this wave
  const int g   = (tid >> 4) & 3;   // cell slot within the wave's quad
  const int f4  = (tid & 15) * 4;   // owned channel quad: ch f4..f4+3
  const int gsh = g * 8;            // byte shift to extract cell g from packed cells
  const bool g01 = (g < 2), g02 = (g & 1) == 0;
  __syncthreads();

  #pragma unroll 2
  for(int e = e0; e < e1; ++e){
    const float4 q  = gw[e];
    const int4   md = gmz[e];
    const float zA = __int_as_float(md.x);
    const float z  = wv ? (1.f - zA) : zA;
    const int   cp = wv ? md.z : md.y;
    float4 v = *(const float4*)(feat + (size_t)md.w*64 + f4);
    if(RELU){
      v.x = fmaxf(v.x, 0.f); v.y = fmaxf(v.y, 0.f);
      v.z = fmaxf(v.z, 0.f); v.w = fmaxf(v.w, 0.f);
    }
    const int   cell = (cp >> gsh) & 255;
    const float qa = g01 ? q.x : q.z;
    const float qb = g01 ? q.y : q.w;
    const float w  = (g02 ? qa : qb) * z;
    float4* p = (float4*)&Bl[(cell << 6) + f4];
    float4 o = *p;
    o.x = fmaf(w, v.x, o.x); o.y = fmaf(w, v.y, o.y);
    o.z = fmaf(w, v.z, o.z); o.w = fmaf(w, v.w, o.w);
    *p = o;
  }
  __syncthreads();

  if(!OUT3){
    float* Bg = B + (size_t)blockIdx.x*BSZ;
    for(int j = tid*4; j < BSZ; j += 512)
      *(float4*)&Bg[j] = *(const float4*)&Bl[j];
  } else {
    float s0=0.f, s1=0.f, s2=0.f;
    for(int j = tid; j < BSZ; j += 128){
      float v = Bl[j];
      s0 = fmaf(v, W3[j*3+0], s0);
      s1 = fmaf(v, W3[j*3+1], s1);
      s2 = fmaf(v, W3[j*3+2], s2);
    }
    #pragma unroll
    for(int off = 32; off > 0; off >>= 1){
      s0 += __shfl_down(s0, off);
      s1 += __shfl_down(s1, off);
      s2 += __shfl_down(s2, off);
    }
    if((tid & 63) == 0){
      red[wv*4+0] = s0; red[wv*4+1] = s1; red[wv*4+2] = s2;
    }
    __syncthreads();
    if(tid == 0 && node < NREAL){
      out[node*3+0] += (red[0]+red[4])*(1.f/128.f);
      out[node*3+1] += (red[1]+red[5])*(1.f/128.f);
      out[node*3+2] += (red[2]+red[6])*(1.f/128.f);
    }
  }
}

// ------- scatter CIN=96: float2 channel pairs (48 lanes), z-parity waves, barrier-free ----
template<int RELU>
__global__ __launch_bounds__(128) void k_scat96(
    const float* __restrict__ feat, const float4* __restrict__ gw,
    const int4* __restrict__ gmz, const int* __restrict__ row_start,
    float* __restrict__ B, int node_base)
{
  constexpr int CIN = 96, BSZ = KK*CIN, NP = 48;
  __shared__ __align__(16) float Bl[BSZ];
  const int tid  = threadIdx.x;
  const int node = node_base + blockIdx.x;

  for(int j = tid*4; j < BSZ; j += 512)
    *(float4*)&Bl[j] = make_float4(0.f,0.f,0.f,0.f);

  const int e0 = row_start[node], e1 = row_start[node+1];
  const int wv   = tid >> 6;
  const int lane = tid & 63;
  const bool act = (lane < NP);
  float2* Bp2 = (float2*)Bl;
  __syncthreads();

  if(act){
    #pragma unroll 2
    for(int e = e0; e < e1; ++e){
      const float4 q  = gw[e];
      const int4   md = gmz[e];
      const float zA = __int_as_float(md.x);
      const float z  = wv ? (1.f - zA) : zA;
      const int   cp = wv ? md.z : md.y;
      float2 v2 = ((const float2*)(feat + (size_t)md.w*CIN))[lane];
      if(RELU){ v2.x = fmaxf(v2.x,0.f); v2.y = fmaxf(v2.y,0.f); }
      v2.x *= z; v2.y *= z;
      const int b0 = ( cp        & 255)*NP + lane;
      const int b1 = ((cp >> 8)  & 255)*NP + lane;
      const int b2 = ((cp >> 16) & 255)*NP + lane;
      const int b3 = (((unsigned)cp) >> 24)*NP + lane;
      float2 o0 = Bp2[b0], o1 = Bp2[b1], o2 = Bp2[b2], o3 = Bp2[b3];
      o0.x = fmaf(q.x, v2.x, o0.x); o0.y = fmaf(q.x, v2.y, o0.y);
      o1.x = fmaf(q.y, v2.x, o1.x); o1.y = fmaf(q.y, v2.y, o1.y);
      o2.x = fmaf(q.z, v2.x, o2.x); o2.y = fmaf(q.z, v2.y, o2.y);
      o3.x = fmaf(q.w, v2.x, o3.x); o3.y = fmaf(q.w, v2.y, o3.y);
      Bp2[b0] = o0; Bp2[b1] = o1; Bp2[b2] = o2; Bp2[b3] = o3;
    }
  }
  __syncthreads();

  float* Bg = B + (size_t)blockIdx.x*BSZ;
  for(int j = tid*4; j < BSZ; j += 512)
    *(float4*)&Bg[j] = *(const float4*)&Bl[j];
}

// ------- scatter CIN=13: 4 edge-slots/wave (slot-private copies), z-parity waves ----------
__global__ __launch_bounds__(128) void k_scat13(
    const float* __restrict__ feat, const float4* __restrict__ gw,
    const int4* __restrict__ gmz, const int* __restrict__ row_start,
    float* __restrict__ B, int node_base)
{
  constexpr int CIN = 13, BSZ = KK*CIN, ESW = 4, CSTRIDE = BSZ + 8;
  __shared__ __align__(16) float Bl[ESW*CSTRIDE];
  const int tid  = threadIdx.x;
  const int node = node_base + blockIdx.x;

  for(int j = tid; j < ESW*CSTRIDE; j += 128) Bl[j] = 0.f;

  const int e0 = row_start[node], e1 = row_start[node+1];
  const int wv   = tid >> 6;
  const int lane = tid & 63;
  const int slot = lane >> 4;
  const int c    = lane & 15;
  const bool act = (c < CIN);
  float* Bp = Bl + slot*CSTRIDE;
  __syncthreads();

  if(act){
    for(int e = e0 + slot; e < e1; e += ESW){
      const float4 q  = gw[e];
      const int4   md = gmz[e];
      const float zA = __int_as_float(md.x);
      const float z  = wv ? (1.f - zA) : zA;
      const int   cp = wv ? md.z : md.y;
      float v = feat[(size_t)md.w*CIN + c] * z;
      const int b0 = ( cp        & 255)*CIN + c;
      const int b1 = ((cp >> 8)  & 255)*CIN + c;
      const int b2 = ((cp >> 16) & 255)*CIN + c;
      const int b3 = (((unsigned)cp) >> 24)*CIN + c;
      float o0 = Bp[b0], o1 = Bp[b1], o2 = Bp[b2], o3 = Bp[b3];
      o0 = fmaf(q.x, v, o0); o1 = fmaf(q.y, v, o1);
      o2 = fmaf(q.z, v, o2); o3 = fmaf(q.w, v, o3);
      Bp[b0] = o0; Bp[b1] = o1; Bp[b2] = o2; Bp[b3] = o3;
    }
  }
  __syncthreads();

  float* Bg = B + (size_t)blockIdx.x*BSZ;
  for(int j = tid*4; j < BSZ; j += 512){
    float4 a = *(const float4*)&Bl[j];
    #pragma unroll
    for(int k = 1; k < ESW; ++k){
      const float4 t = *(const float4*)&Bl[k*CSTRIDE + j];
      a.x += t.x; a.y += t.y; a.z += t.z; a.w += t.w;
    }
    *(float4*)&Bg[j] = a;
  }
}

// ---- GEMM, no atomics: P[s][node][64] = sum_{k in split s} A[row,k]*W[k,o]
__global__ __launch_bounds__(256) void k_gemm2(
    const float* __restrict__ A, const float* __restrict__ W,
    float* __restrict__ P, int M, int Kd, int node_base, int ktiles_per)
{
  __shared__ __align__(16) float As[16][68];   // [k][row]
  __shared__ __align__(16) float Ws[16][64];   // [k][col]
  const int tid = threadIdx.x;
  const int mbase = blockIdx.x * 64;
  const int s = blockIdx.y;
  const int kt0 = s * ktiles_per * 16;
  const int kt1 = min(Kd, kt0 + ktiles_per*16);
  const int ty = tid >> 4, tx = tid & 15;
  const int arow = tid >> 2, ako = (tid & 3) * 4;
  const int wk = tid >> 4,  wc = (tid & 15) * 4;

  float acc[4][4];
  #pragma unroll
  for(int i=0;i<4;++i)
    #pragma unroll
    for(int j=0;j<4;++j) acc[i][j] = 0.f;

  for(int kt = kt0; kt < kt1; kt += 16){
    float4 av = make_float4(0.f,0.f,0.f,0.f);
    const int grow = mbase + arow;
    if(grow < M) av = *(const float4*)(A + (size_t)grow*Kd + kt + ako);
    const float4 wv = *(const float4*)(W + (size_t)(kt + wk)*64 + wc);
    As[ako+0][arow]=av.x; As[ako+1][arow]=av.y; As[ako+2][arow]=av.z; As[ako+3][arow]=av.w;
    *(float4*)&Ws[wk][wc] = wv;
    __syncthreads();
    #pragma unroll
    for(int kk = 0; kk < 16; ++kk){
      const float4 a = *(const float4*)&As[kk][ty*4];
      const float4 b = *(const float4*)&Ws[kk][tx*4];
      const float aa[4] = {a.x,a.y,a.z,a.w};
      const float bb[4] = {b.x,b.y,b.z,b.w};
      #pragma unroll
      for(int i=0;i<4;++i)
        #pragma unroll
        for(int j=0;j<4;++j) acc[i][j] = fmaf(aa[i], bb[j], acc[i][j]);
    }
    __syncthreads();
  }

  #pragma unroll
  for(int i=0;i<4;++i){
    const int row = mbase + ty*4 + i;
    if(row < M)
      *(float4*)(P + ((size_t)s*NPTS + node_base + row)*64 + tx*4) = *(float4*)&acc[i][0];
  }
}

// ---- combine partials: x[node*ldout+colofs+o] += sum_s P[s][node][o]
template<int S>
__global__ void k_combine(const float* __restrict__ P, float* __restrict__ x,
                          int ldout, int colofs)
{
  int idx = blockIdx.x*blockDim.x + threadIdx.x;
  if(idx >= NPTS*16) return;
  int node = idx >> 4, c4 = (idx & 15) * 4;
  float4 s = *(const float4*)(P + (size_t)node*64 + c4);
  #pragma unroll
  for(int k=1;k<S;++k){
    float4 t = *(const float4*)(P + ((size_t)k*NPTS + node)*64 + c4);
    s.x+=t.x; s.y+=t.y; s.z+=t.z; s.w+=t.w;
  }
  float* xp = x + (size_t)node*ldout + colofs + c4;
  float4 o = *(float4*)xp;
  o.x+=s.x; o.y+=s.y; o.z+=s.z; o.w+=s.w;
  *(float4*)xp = o;
}

// ---------------- dense paths ----------------
__global__ void k_dense0(const float* __restrict__ f, const float* __restrict__ dW,
                         const float* __restrict__ db, const float* __restrict__ cb0,
                         float* __restrict__ out)
{
  int idx = blockIdx.x*blockDim.x + threadIdx.x;
  if(idx >= NPTS*96) return;
  int i = idx/96, c = idx - i*96;
  if(c < 64){ out[idx] = cb0[c]; return; }
  int o = c - 64;
  float s = db[o];
  const float* row = f + (size_t)i*13;
  #pragma unroll
  for(int j=0;j<13;++j) s = fmaf(row[j], dW[j*32+o], s);
  out[idx] = s;
}

__global__ void k_dense(const float* __restrict__ in, int cin,
                        const float* __restrict__ dW, const float* __restrict__ db,
                        const float* __restrict__ cb, const float* __restrict__ resid,
                        float* __restrict__ out)
{
  int idx = blockIdx.x*blockDim.x + threadIdx.x;
  if(idx >= NPTS*64) return;
  int i = idx >> 6, o = idx & 63;
  float s = db[o] + cb[o];
  if(resid) s += resid[idx];
  const float* row = in + (size_t)i*cin;
  for(int c=0;c<cin;++c) s = fmaf(fmaxf(row[c],0.f), dW[c*64+o], s);
  out[idx] = s;
}

__global__ void k_dense3(const float* __restrict__ x2, const float* __restrict__ dW,
                         const float* __restrict__ db, const float* __restrict__ cb,
                         float* __restrict__ out)
{
  int idx = blockIdx.x*blockDim.x + threadIdx.x;
  if(idx >= NREAL*3) return;
  int i = idx/3, o = idx - i*3;
  float s = db[o] + cb[o];
  const float* row = x2 + (size_t)i*64;
  for(int c=0;c<64;++c) s = fmaf(fmaxf(row[c],0.f), dW[c*3+o], s);
  out[idx] = s * (1.f/128.f);
}

// ---------------- host ----------------
static inline size_t alup(size_t x){ return (x + 255) & ~(size_t)255; }

static inline int calc_rows(size_t bcap, int cin, int want){
  size_t perrow = (size_t)KK * cin * 4;
  size_t r = (perrow > 0) ? bcap / perrow : 0;
  if(r >= (size_t)want) return want;
  r = (r / 128) * 128;
  if(r < 128) r = 128;
  return (int)r;
}

extern "C" void kernel_launch(void* const* d_in, const int* in_sizes, int n_in,
                              void* d_out, int out_size, void* d_ws, size_t ws_size,
                              hipStream_t stream)
{
  const float* pos   = (const float*)d_in[0];
  const float* feats = (const float*)d_in[1];
  const int*   esrc  = (const int*)d_in[2];
  const int*   edst  = (const int*)d_in[3];
  const float* c0w = (const float*)d_in[4];
  const float* c0b = (const float*)d_in[5];
  const float* d0w = (const float*)d_in[6];
  const float* d0b = (const float*)d_in[7];
  const float* c1w = (const float*)d_in[8];
  const float* c1b = (const float*)d_in[9];
  const float* d1w = (const float*)d_in[10];
  const float* d1b = (const float*)d_in[11];
  const float* c2w = (const float*)d_in[12];
  const float* c2b = (const float*)d_in[13];
  const float* d2w = (const float*)d_in[14];
  const float* d2b = (const float*)d_in[15];
  const float* c3w = (const float*)d_in[16];
  const float* c3b = (const float*)d_in[17];
  const float* d3w = (const float*)d_in[18];
  const float* d3b = (const float*)d_in[19];
  float* out = (float*)d_out;

  char* w = (char*)d_ws;
  size_t off = 0;
  float* f  = (float*)(w+off); off += alup((size_t)NPTS*13*4);
  float* x0 = (float*)(w+off); off += alup((size_t)NPTS*96*4);
  float* x1 = (float*)(w+off); off += alup((size_t)NPTS*64*4);
  float* x2 = (float*)(w+off); off += alup((size_t)NPTS*64*4);
  int* row_start = (int*)(w+off); off += alup((size_t)(NPTS+1)*4);
  int* ereal = (int*)(w+off);     off += alup(16);
  float4* gw = (float4*)(w+off);  off += alup((size_t)EPAD*16);    // per-edge xy weights
  int4*  gmz = (int4*)(w+off);    off += alup((size_t)EPAD*16);    // per-edge zA+cells+dst
  float* P  = (float*)(w+off); off += alup((size_t)8*NPTS*64*4);   // split-K partials (S<=8)
  float* B = (float*)(w+off);
  size_t bcap = (ws_size > off) ? (ws_size - off) : 0;

  k_find_ereal<<<1,1,0,stream>>>(edst, ereal);
  k_csr<<<(NPTS+1+255)/256,256,0,stream>>>(esrc, ereal, row_start);
  k_build_f<<<(NPTS*13+255)/256,256,0,stream>>>(feats, f);
  k_geom<<<(EPAD+255)/256,256,0,stream>>>(pos, esrc, edst, gw, gmz);

  // ---- layer 0: x0[:,0:64] = cconv0(f)+c0b ; x0[:,64:96] = f@d0w+d0b  (chunk 8192)
  k_dense0<<<(NPTS*96+255)/256,256,0,stream>>>(f, d0w, d0b, c0b, x0);
  {
    int rows = calc_rows(bcap, 13, 8192);
    for(int base = 0; base < NPTS; base += rows){
      int m = (NPTS - base < rows) ? (NPTS - base) : rows;
      k_scat13<<<m,128,0,stream>>>(f, gw, gmz, row_start, B, base);
      k_gemm2<<<dim3((m+63)/64, 8),256,0,stream>>>(B, c0w, P, m, 832, base, 7);
    }
    k_combine<8><<<(NPTS*16+255)/256,256,0,stream>>>(P, x0, 96, 0);
  }

  // ---- layer 1: x1 = cconv1(relu(x0)) + relu(x0)@d1w + d1b + c1b   (chunk 4096)
  k_dense<<<(NPTS*64+255)/256,256,0,stream>>>(x0, 96, d1w, d1b, c1b, nullptr, x1);
  {
    int rows = calc_rows(bcap, 96, 4096);
    for(int base = 0; base < NPTS; base += rows){
      int m = (NPTS - base < rows) ? (NPTS - base) : rows;
      k_scat96<1><<<m,128,0,stream>>>(x0, gw, gmz, row_start, B, base);
      k_gemm2<<<dim3((m+63)/64, 8),256,0,stream>>>(B, c1w, P, m, 6144, base, 48);
    }
    k_combine<8><<<(NPTS*16+255)/256,256,0,stream>>>(P, x1, 64, 0);
  }

  // ---- layer 2: x2 = cconv2(relu(x1)) + relu(x1)@d2w + d2b + c2b + x1  (chunk 4096)
  k_dense<<<(NPTS*64+255)/256,256,0,stream>>>(x1, 64, d2w, d2b, c2b, x1, x2);
  {
    int rows = calc_rows(bcap, 64, 4096);
    for(int base = 0; base < NPTS; base += rows){
      int m = (NPTS - base < rows) ? (NPTS - base) : rows;
      k_scat64<1,0><<<m,128,0,stream>>>(x1, gw, gmz, row_start, B, base, nullptr, nullptr);
      k_gemm2<<<dim3((m+63)/64, 8),256,0,stream>>>(B, c2w, P, m, 4096, base, 32);
    }
    k_combine<8><<<(NPTS*16+255)/256,256,0,stream>>>(P, x2, 64, 0);
  }

  // ---- layer 3 (fused): out = dense3 part, then scatter adds conv3 GEMV directly
  k_dense3<<<(NREAL*3+255)/256,256,0,stream>>>(x2, d3w, d3b, c3b, out);
  k_scat64<1,1><<<NPTS,128,0,stream>>>(x2, gw, gmz, row_start, nullptr, 0, c3w, out);
}